// Round 1
// baseline (615.885 us; speedup 1.0000x reference)
//
#include <hip/hip_runtime.h>

// edgeNet: per-node factorization of the edge MLP.
//   a1[n] = relu(feat[n]@W_nb  + b_nb ) @ W_att1[:128]  + b_att1   (bias folded)
//   a2[n] = relu(feat[n]@W_self+ b_self) @ W_att1[128:]
//   out[e] = relu(a1[e0] + a2[e1]) . W_att2 + b_att2
// 12x fewer GEMM rows than the reference's per-edge formulation.

#define N_NODES 50000
#define D_FEAT  128
#define H1      128
#define H2      64
#define N_EDGES 600000
#define TILE_N  32
#define SF_LD   (D_FEAT + 4)   // +4 pad: (132*nl + k) % 32 spans 8 banks for nl=0..7
#define SH_LD   (H1 + 4)

__global__ void node_kernel(
    const float* __restrict__ feat,
    const float* __restrict__ Wnb,  const float* __restrict__ bnb,
    const float* __restrict__ Wsf,  const float* __restrict__ bsf,
    const float* __restrict__ Wat1, const float* __restrict__ bat1,
    float* __restrict__ a1, float* __restrict__ a2)
{
    __shared__ float sf [TILE_N][SF_LD];   // 16.5 KB
    __shared__ float sh1[TILE_N][SH_LD];   // 16.5 KB
    __shared__ float sh2[TILE_N][SH_LD];   // 16.5 KB -> 49.5 KB total, 3 blocks/CU

    const int t  = threadIdx.x;
    const int n0 = blockIdx.x * TILE_N;

    // ---- stage features tile (coalesced float4) ----
    for (int i = t; i < TILE_N * (D_FEAT / 4); i += 256) {
        const int node = i >> 5;      // / (D_FEAT/4)
        const int c4   = i & 31;
        const int gn   = n0 + node;
        float4 v = make_float4(0.f, 0.f, 0.f, 0.f);
        if (gn < N_NODES)
            v = ((const float4*)(feat + (size_t)gn * D_FEAT))[c4];
        ((float4*)&sf[node][0])[c4] = v;   // row stride 132 floats = 528 B, 16B-aligned
    }
    __syncthreads();

    // ---- stage 1: h1 = relu(f@Wnb+b), h2 = relu(f@Wsf+b) ----
    {
        const int cg = t & 7;    // 8 col-groups x 16 cols
        const int nl = t >> 3;   // 32 nodes

        float4 acc1[4], acc2[4];
        #pragma unroll
        for (int j = 0; j < 4; ++j) {
            acc1[j] = ((const float4*)bnb)[cg * 4 + j];
            acc2[j] = ((const float4*)bsf)[cg * 4 + j];
        }
        for (int k = 0; k < D_FEAT; ++k) {
            const float fk = sf[nl][k];                      // broadcast, conflict-free
            const float4* w1 = (const float4*)(Wnb + k * H1) + cg * 4;
            const float4* w2 = (const float4*)(Wsf + k * H1) + cg * 4;
            #pragma unroll
            for (int j = 0; j < 4; ++j) {
                const float4 a = w1[j];
                const float4 b = w2[j];
                acc1[j].x += fk * a.x; acc1[j].y += fk * a.y;
                acc1[j].z += fk * a.z; acc1[j].w += fk * a.w;
                acc2[j].x += fk * b.x; acc2[j].y += fk * b.y;
                acc2[j].z += fk * b.z; acc2[j].w += fk * b.w;
            }
        }
        #pragma unroll
        for (int j = 0; j < 4; ++j) {
            const int c = cg * 16 + j * 4;
            sh1[nl][c + 0] = fmaxf(acc1[j].x, 0.f);
            sh1[nl][c + 1] = fmaxf(acc1[j].y, 0.f);
            sh1[nl][c + 2] = fmaxf(acc1[j].z, 0.f);
            sh1[nl][c + 3] = fmaxf(acc1[j].w, 0.f);
            sh2[nl][c + 0] = fmaxf(acc2[j].x, 0.f);
            sh2[nl][c + 1] = fmaxf(acc2[j].y, 0.f);
            sh2[nl][c + 2] = fmaxf(acc2[j].z, 0.f);
            sh2[nl][c + 3] = fmaxf(acc2[j].w, 0.f);
        }
    }
    __syncthreads();

    // ---- stage 2: a1 = h1 @ Wat1[:128] (+bat1), a2 = h2 @ Wat1[128:] ----
    {
        const int cg = t & 7;    // 8 col-groups x 8 cols of H2=64
        const int nl = t >> 3;   // 32 nodes

        float4 aa1[2], aa2[2];
        aa1[0] = ((const float4*)bat1)[cg * 2 + 0];   // fold b_att1 into a1
        aa1[1] = ((const float4*)bat1)[cg * 2 + 1];
        aa2[0] = make_float4(0.f, 0.f, 0.f, 0.f);
        aa2[1] = make_float4(0.f, 0.f, 0.f, 0.f);

        for (int k = 0; k < H1; ++k) {
            const float h1k = sh1[nl][k];
            const float h2k = sh2[nl][k];
            const float4* wA = (const float4*)(Wat1 + (size_t)k        * H2) + cg * 2;
            const float4* wB = (const float4*)(Wat1 + (size_t)(H1 + k) * H2) + cg * 2;
            #pragma unroll
            for (int j = 0; j < 2; ++j) {
                const float4 a = wA[j];
                const float4 b = wB[j];
                aa1[j].x += h1k * a.x; aa1[j].y += h1k * a.y;
                aa1[j].z += h1k * a.z; aa1[j].w += h1k * a.w;
                aa2[j].x += h2k * b.x; aa2[j].y += h2k * b.y;
                aa2[j].z += h2k * b.z; aa2[j].w += h2k * b.w;
            }
        }
        const int gn = n0 + nl;
        if (gn < N_NODES) {
            float4* p1 = (float4*)(a1 + (size_t)gn * H2) + cg * 2;
            float4* p2 = (float4*)(a2 + (size_t)gn * H2) + cg * 2;
            p1[0] = aa1[0]; p1[1] = aa1[1];
            p2[0] = aa2[0]; p2[1] = aa2[1];
        }
    }
}

// 16 lanes per edge; each lane handles 4 of the 64 hidden dims via float4.
__global__ void edge_kernel(
    const int* __restrict__ edges,
    const float* __restrict__ a1, const float* __restrict__ a2,
    const float* __restrict__ Wat2, const float* __restrict__ bat2,
    float* __restrict__ out)
{
    const int t      = threadIdx.x;
    const int lane16 = t & 15;
    const int group  = t >> 4;                  // 16 edges per 256-thread block

    const float4 w    = ((const float4*)Wat2)[lane16];
    const float  bias = bat2[0];

    const int eid = blockIdx.x * 16 + group;
    if (eid >= N_EDGES) return;

    const int e0 = edges[2 * eid];
    const int e1 = edges[2 * eid + 1];

    const float4 v1 = ((const float4*)(a1 + (size_t)e0 * H2))[lane16];
    const float4 v2 = ((const float4*)(a2 + (size_t)e1 * H2))[lane16];

    const float tx = fmaxf(v1.x + v2.x, 0.f);
    const float ty = fmaxf(v1.y + v2.y, 0.f);
    const float tz = fmaxf(v1.z + v2.z, 0.f);
    const float tw = fmaxf(v1.w + v2.w, 0.f);

    float s = tx * w.x + ty * w.y + tz * w.z + tw * w.w;
    s += __shfl_down(s, 8, 16);
    s += __shfl_down(s, 4, 16);
    s += __shfl_down(s, 2, 16);
    s += __shfl_down(s, 1, 16);

    if (lane16 == 0) out[eid] = s + bias;
}

extern "C" void kernel_launch(void* const* d_in, const int* in_sizes, int n_in,
                              void* d_out, int out_size, void* d_ws, size_t ws_size,
                              hipStream_t stream) {
    const float* feat = (const float*)d_in[0];
    const int*   edges = (const int*)d_in[1];   // harness materializes integer inputs as int32
    const float* Wnb  = (const float*)d_in[2];
    const float* bnb  = (const float*)d_in[3];
    const float* Wsf  = (const float*)d_in[4];
    const float* bsf  = (const float*)d_in[5];
    const float* Wat1 = (const float*)d_in[6];
    const float* bat1 = (const float*)d_in[7];
    const float* Wat2 = (const float*)d_in[8];
    const float* bat2 = (const float*)d_in[9];
    float* out = (float*)d_out;

    float* a1 = (float*)d_ws;                       // 50000*64 f32 = 12.8 MB
    float* a2 = a1 + (size_t)N_NODES * H2;          // +12.8 MB

    const int node_blocks = (N_NODES + TILE_N - 1) / TILE_N;   // 1563
    node_kernel<<<node_blocks, 256, 0, stream>>>(feat, Wnb, bnb, Wsf, bsf,
                                                 Wat1, bat1, a1, a2);

    const int edge_blocks = (N_EDGES + 15) / 16;               // 37500
    edge_kernel<<<edge_blocks, 256, 0, stream>>>(edges, a1, a2, Wat2, bat2, out);
}

// Round 2
// 196.195 us; speedup vs baseline: 3.1391x; 3.1391x over previous
//
#include <hip/hip_runtime.h>

// edgeNet, round 2.
// Per-node factorization (12x fewer GEMM rows than reference):
//   a1[n] = relu(feat[n]@W_nb  + b_nb ) @ W_att1[:128] + b_att1
//   a2[n] = relu(feat[n]@W_self+ b_self) @ W_att1[128:]
//   out[e] = relu(a1[e0] + a2[e1]) . W_att2 + b_att2
// Node kernel: register-blocked fp32 GEMM (4 nodes x 8 cols per thread,
// transposed LDS feature tile, prefetched weight loads). a1/a2 stored bf16
// to halve the edge-stage gather traffic.

#define N_NODES 50000
#define D_FEAT  128
#define H1      128
#define H2      64
#define N_EDGES 600000
#define TILE    32
#define LDT     36   // padded LDS row stride (floats); 144 B = multiple of 16

typedef unsigned short bf16_t;

static __device__ __forceinline__ bf16_t f2bf(float f) {
    union { float f; unsigned u; } v; v.f = f;
    unsigned r = v.u + 0x7fffu + ((v.u >> 16) & 1u);   // round-to-nearest-even
    return (bf16_t)(r >> 16);
}
static __device__ __forceinline__ float bflo(unsigned u) {
    union { unsigned u; float f; } v; v.u = u << 16; return v.f;
}
static __device__ __forceinline__ float bfhi(unsigned u) {
    union { unsigned u; float f; } v; v.u = u & 0xffff0000u; return v.f;
}

#define GETC(v,i) ((i)==0?(v).x:((i)==1?(v).y:((i)==2?(v).z:(v).w)))

__global__ __launch_bounds__(256, 2) void node_kernel(
    const float* __restrict__ feat,
    const float* __restrict__ Wnb,  const float* __restrict__ bnb,
    const float* __restrict__ Wsf,  const float* __restrict__ bsf,
    const float* __restrict__ Wat1, const float* __restrict__ bat1,
    bf16_t* __restrict__ a1, bf16_t* __restrict__ a2)
{
    __shared__ float sfT [D_FEAT][LDT];   // features, transposed  (18.4 KB)
    __shared__ float shT1[H1][LDT];       // relu(f@Wnb+b), transposed
    __shared__ float shT2[H1][LDT];       // relu(f@Wsf+b), transposed
    // total 55.3 KB -> 2 blocks/CU

    const int t    = threadIdx.x;
    const int n0   = blockIdx.x * TILE;
    const int tx   = t & 31;
    const int ty4  = (t >> 5) * 4;        // node group base: 0,4,...,28
    const int m    = tx & 15;
    const bool first = tx < 16;           // lanes 0-15: h1/a1 path, 16-31: h2/a2

    // ---- stage features, transposed, coalesced loads ----
    {
        const int node = t >> 3;          // 0..31
        const int gn   = n0 + node;
        const int c0   = (t & 7) * 16;    // 16 floats per thread
        #pragma unroll
        for (int j = 0; j < 4; ++j) {
            float4 v = make_float4(0.f, 0.f, 0.f, 0.f);
            if (gn < N_NODES)
                v = *((const float4*)(feat + (size_t)gn * D_FEAT + c0 + j * 4));
            const int c = c0 + j * 4;
            sfT[c+0][node] = v.x; sfT[c+1][node] = v.y;
            sfT[c+2][node] = v.z; sfT[c+3][node] = v.w;
        }
    }
    __syncthreads();

    // ---- stage 1: h = relu(f @ W + b), 4 nodes x 8 cols per thread ----
    {
        const float* W  = first ? Wnb : Wsf;
        const float* bv = first ? bnb : bsf;
        const int col0  = m * 8;

        float4 acc[8];                    // acc[c] = 4 nodes of column col0+c
        #pragma unroll
        for (int j = 0; j < 8; ++j) {
            const float b = bv[col0 + j];
            acc[j] = make_float4(b, b, b, b);
        }

        float4 wa = *((const float4*)(W + col0));
        float4 wb = *((const float4*)(W + col0 + 4));
        float4 f  = *((const float4*)&sfT[0][ty4]);

        for (int k = 0; k < D_FEAT; ++k) {
            const float4 wac = wa, wbc = wb, fc = f;
            const int kn = (k + 1) & (D_FEAT - 1);       // prefetch (wraps once, harmless)
            const float* Wr = W + kn * H1 + col0;
            wa = *((const float4*)Wr);
            wb = *((const float4*)(Wr + 4));
            f  = *((const float4*)&sfT[kn][ty4]);

            acc[0].x += fc.x*wac.x; acc[0].y += fc.y*wac.x; acc[0].z += fc.z*wac.x; acc[0].w += fc.w*wac.x;
            acc[1].x += fc.x*wac.y; acc[1].y += fc.y*wac.y; acc[1].z += fc.z*wac.y; acc[1].w += fc.w*wac.y;
            acc[2].x += fc.x*wac.z; acc[2].y += fc.y*wac.z; acc[2].z += fc.z*wac.z; acc[2].w += fc.w*wac.z;
            acc[3].x += fc.x*wac.w; acc[3].y += fc.y*wac.w; acc[3].z += fc.z*wac.w; acc[3].w += fc.w*wac.w;
            acc[4].x += fc.x*wbc.x; acc[4].y += fc.y*wbc.x; acc[4].z += fc.z*wbc.x; acc[4].w += fc.w*wbc.x;
            acc[5].x += fc.x*wbc.y; acc[5].y += fc.y*wbc.y; acc[5].z += fc.z*wbc.y; acc[5].w += fc.w*wbc.y;
            acc[6].x += fc.x*wbc.z; acc[6].y += fc.y*wbc.z; acc[6].z += fc.z*wbc.z; acc[6].w += fc.w*wbc.z;
            acc[7].x += fc.x*wbc.w; acc[7].y += fc.y*wbc.w; acc[7].z += fc.z*wbc.w; acc[7].w += fc.w*wbc.w;
        }

        float (*sh)[LDT] = first ? shT1 : shT2;
        #pragma unroll
        for (int j = 0; j < 8; ++j) {
            float4 v = acc[j];
            v.x = fmaxf(v.x, 0.f); v.y = fmaxf(v.y, 0.f);
            v.z = fmaxf(v.z, 0.f); v.w = fmaxf(v.w, 0.f);
            *((float4*)&sh[col0 + j][ty4]) = v;          // b128 write
        }
    }
    __syncthreads();

    // ---- stage 2: a = h @ Wat1_half (+bias), 4 nodes x 4 cols per thread ----
    {
        const float (*shS)[LDT] = first ? shT1 : shT2;
        const float* W2 = Wat1 + (first ? 0 : (size_t)H1 * H2);
        const int c0 = m * 4;

        float4 acc[4];
        #pragma unroll
        for (int j = 0; j < 4; ++j) {
            const float b = first ? bat1[c0 + j] : 0.f;  // fold b_att1 into a1
            acc[j] = make_float4(b, b, b, b);
        }

        float4 w = *((const float4*)(W2 + c0));
        float4 f = *((const float4*)&shS[0][ty4]);

        for (int k = 0; k < H1; ++k) {
            const float4 wc = w, fc = f;
            const int kn = (k + 1) & (H1 - 1);
            w = *((const float4*)(W2 + kn * H2 + c0));
            f = *((const float4*)&shS[kn][ty4]);

            acc[0].x += fc.x*wc.x; acc[0].y += fc.y*wc.x; acc[0].z += fc.z*wc.x; acc[0].w += fc.w*wc.x;
            acc[1].x += fc.x*wc.y; acc[1].y += fc.y*wc.y; acc[1].z += fc.z*wc.y; acc[1].w += fc.w*wc.y;
            acc[2].x += fc.x*wc.z; acc[2].y += fc.y*wc.z; acc[2].z += fc.z*wc.z; acc[2].w += fc.w*wc.z;
            acc[3].x += fc.x*wc.w; acc[3].y += fc.y*wc.w; acc[3].z += fc.z*wc.w; acc[3].w += fc.w*wc.w;
        }

        bf16_t* A = first ? a1 : a2;
        #pragma unroll
        for (int n = 0; n < 4; ++n) {
            const int gn = n0 + ty4 + n;
            if (gn < N_NODES) {
                ushort4 pk;
                pk.x = f2bf(GETC(acc[0], n));
                pk.y = f2bf(GETC(acc[1], n));
                pk.z = f2bf(GETC(acc[2], n));
                pk.w = f2bf(GETC(acc[3], n));
                ((ushort4*)(A + (size_t)gn * H2))[m] = pk;   // 8 B store, rows coalesce
            }
        }
    }
}

// 8 lanes per edge; each lane loads 8 bf16 (16 B) per operand -> one 128 B
// coalesced segment per gathered row.
__global__ __launch_bounds__(256) void edge_kernel(
    const int* __restrict__ edges,
    const bf16_t* __restrict__ a1, const bf16_t* __restrict__ a2,
    const float* __restrict__ Wat2, const float* __restrict__ bat2,
    float* __restrict__ out)
{
    const int t   = threadIdx.x;
    const int l   = t & 7;
    const int eid = blockIdx.x * 32 + (t >> 3);
    if (eid >= N_EDGES) return;

    const float4 w0 = ((const float4*)Wat2)[l * 2 + 0];
    const float4 w1 = ((const float4*)Wat2)[l * 2 + 1];

    const int2 ep = ((const int2*)edges)[eid];
    const uint4 q1 = ((const uint4*)(a1 + (size_t)ep.x * H2))[l];
    const uint4 q2 = ((const uint4*)(a2 + (size_t)ep.y * H2))[l];

    float s = 0.f;
    s += fmaxf(bflo(q1.x) + bflo(q2.x), 0.f) * w0.x;
    s += fmaxf(bfhi(q1.x) + bfhi(q2.x), 0.f) * w0.y;
    s += fmaxf(bflo(q1.y) + bflo(q2.y), 0.f) * w0.z;
    s += fmaxf(bfhi(q1.y) + bfhi(q2.y), 0.f) * w0.w;
    s += fmaxf(bflo(q1.z) + bflo(q2.z), 0.f) * w1.x;
    s += fmaxf(bfhi(q1.z) + bfhi(q2.z), 0.f) * w1.y;
    s += fmaxf(bflo(q1.w) + bflo(q2.w), 0.f) * w1.z;
    s += fmaxf(bfhi(q1.w) + bfhi(q2.w), 0.f) * w1.w;

    s += __shfl_down(s, 4, 8);
    s += __shfl_down(s, 2, 8);
    s += __shfl_down(s, 1, 8);

    if (l == 0) out[eid] = s + bat2[0];
}

extern "C" void kernel_launch(void* const* d_in, const int* in_sizes, int n_in,
                              void* d_out, int out_size, void* d_ws, size_t ws_size,
                              hipStream_t stream) {
    const float* feat  = (const float*)d_in[0];
    const int*   edges = (const int*)d_in[1];
    const float* Wnb   = (const float*)d_in[2];
    const float* bnb   = (const float*)d_in[3];
    const float* Wsf   = (const float*)d_in[4];
    const float* bsf   = (const float*)d_in[5];
    const float* Wat1  = (const float*)d_in[6];
    const float* bat1  = (const float*)d_in[7];
    const float* Wat2  = (const float*)d_in[8];
    const float* bat2  = (const float*)d_in[9];
    float* out = (float*)d_out;

    bf16_t* a1 = (bf16_t*)d_ws;                      // 50000*64 bf16 = 6.4 MB
    bf16_t* a2 = a1 + (size_t)N_NODES * H2;          // +6.4 MB

    const int node_blocks = (N_NODES + TILE - 1) / TILE;   // 1563
    node_kernel<<<node_blocks, 256, 0, stream>>>(feat, Wnb, bnb, Wsf, bsf,
                                                 Wat1, bat1, a1, a2);

    const int edge_blocks = (N_EDGES + 31) / 32;           // 18750
    edge_kernel<<<edge_blocks, 256, 0, stream>>>(edges, a1, a2, Wat2, bat2, out);
}

// Round 3
// 128.841 us; speedup vs baseline: 4.7802x; 1.5228x over previous
//
#include <hip/hip_runtime.h>

// edgeNet, round 3: MFMA node stage.
//   a1[n] = relu(feat[n]@W_nb  + b_nb ) @ W_att1[:128] + b_att1
//   a2[n] = relu(feat[n]@W_self+ b_self) @ W_att1[128:]
//   out[e] = relu(a1[e0] + a2[e1]) . W_att2 + b_att2
//
// Node kernel: bf16 MFMA (16x16x32), 64 nodes/block, 4 waves.
// Stage 1 is computed OPERAND-SWAPPED: D' = W1^T * F^T, so C/D rows are
// h-cols and each lane holds 4 consecutive h-cols -> packed b64 writes into
// the stage-2 A-fragment-major LDS buffer (cheap transpose). All inner-loop
// LDS reads are lane-contiguous 16B (conflict-free). Weights are pre-gathered
// into register fragments (L2-resident).

#define N_NODES 50000
#define D_FEAT  128
#define H1      128
#define H2      64
#define N_EDGES 600000

typedef unsigned short u16;
typedef __attribute__((ext_vector_type(8))) short bf16x8;
typedef __attribute__((ext_vector_type(4))) float f32x4;

union FragU { uint4 u; bf16x8 v; };

static __device__ __forceinline__ unsigned bfpack(float a, float b) {
    union { float f; unsigned u; } x, y; x.f = a; y.f = b;
    unsigned lo = (x.u + 0x7fffu + ((x.u >> 16) & 1u)) >> 16;
    unsigned hi = (y.u + 0x7fffu + ((y.u >> 16) & 1u)) & 0xffff0000u;
    return lo | hi;
}
static __device__ __forceinline__ u16 f2bf(float f) {
    union { float f; unsigned u; } v; v.f = f;
    return (u16)((v.u + 0x7fffu + ((v.u >> 16) & 1u)) >> 16);
}
static __device__ __forceinline__ float bflo(unsigned u) {
    union { unsigned u; float f; } v; v.u = u << 16; return v.f;
}
static __device__ __forceinline__ float bfhi(unsigned u) {
    union { unsigned u; float f; } v; v.u = u & 0xffff0000u; return v.f;
}

__global__ __launch_bounds__(256) void node_kernel(
    const float* __restrict__ feat,
    const float* __restrict__ Wnb,  const float* __restrict__ bnb,
    const float* __restrict__ Wsf,  const float* __restrict__ bsf,
    const float* __restrict__ Wat1, const float* __restrict__ bat1,
    u16* __restrict__ a1, u16* __restrict__ a2)
{
    // Fragment-major LDS: slot = ((subtile*4_or_8 + kchunk)*64 + lane)*8 bf16.
    __shared__ u16 Abuf[4 * 4 * 64 * 8];   // features, A-frag layout (16 KB)
    __shared__ u16 Hbuf[4 * 8 * 64 * 8];   // hidden,   A-frag layout (32 KB)

    const int t    = threadIdx.x;
    const int w    = t >> 6;          // wave 0..3
    const int lane = t & 63;
    const int m    = lane & 15;
    const int q    = lane >> 4;
    const int n0   = blockIdx.x * 64;

    // ---- stage features -> bf16, A-fragment-major (lane reads are stride-1) ----
    #pragma unroll
    for (int s = 0; s < 8; ++s) {
        const int i   = s * 256 + t;        // over 64 rows x 32 float4
        const int row = i >> 5;
        const int c4  = i & 31;
        const int gn  = n0 + row;
        float4 v = make_float4(0.f, 0.f, 0.f, 0.f);
        if (gn < N_NODES)
            v = *((const float4*)(feat + (size_t)gn * D_FEAT + c4 * 4));
        const int k0  = c4 * 4;
        const int kc  = k0 >> 5;
        const int qq  = (k0 >> 3) & 3;
        const int j0  = k0 & 7;             // 0 or 4
        const int idx = (((row >> 4) * 4 + kc) * 64 + (qq * 16 + (row & 15))) * 8 + j0;
        uint2 p; p.x = bfpack(v.x, v.y); p.y = bfpack(v.z, v.w);
        *((uint2*)&Abuf[idx]) = p;
    }

    // ---- pre-gather W1^T A-fragments (wave w owns h-cols [64w, 64w+64)) ----
    FragU w1f[4][4];                        // [h-col subtile][k chunk], 64 VGPRs
    #pragma unroll
    for (int ms = 0; ms < 4; ++ms) {
        const int col = w * 64 + ms * 16 + m;     // h-col 0..255
        const float* src = (col < H1) ? (Wnb + col) : (Wsf + (col - H1));
        #pragma unroll
        for (int kc = 0; kc < 4; ++kc) {
            const int k0 = kc * 32 + q * 8;
            float e[8];
            #pragma unroll
            for (int j = 0; j < 8; ++j) e[j] = src[(size_t)(k0 + j) * H1];
            w1f[ms][kc].u = make_uint4(bfpack(e[0], e[1]), bfpack(e[2], e[3]),
                                       bfpack(e[4], e[5]), bfpack(e[6], e[7]));
        }
    }

    f32x4 acc1[4][4];                       // [h-col subtile][node subtile]
    #pragma unroll
    for (int i = 0; i < 4; ++i)
        #pragma unroll
        for (int j = 0; j < 4; ++j)
            acc1[i][j] = (f32x4){0.f, 0.f, 0.f, 0.f};

    __syncthreads();

    // ---- stage 1 (swapped): D' = W1^T * F^T -> h^T tiles ----
    #pragma unroll
    for (int kc = 0; kc < 4; ++kc) {
        #pragma unroll
        for (int ns = 0; ns < 4; ++ns) {
            FragU ff; ff.u = *((const uint4*)&Abuf[((ns * 4 + kc) * 64 + lane) * 8]);
            #pragma unroll
            for (int ms = 0; ms < 4; ++ms)
                acc1[ms][ns] = __builtin_amdgcn_mfma_f32_16x16x32_bf16(
                    w1f[ms][kc].v, ff.v, acc1[ms][ns], 0, 0, 0);
        }
    }

    // ---- epilogue 1: bias + relu, pack 4 consecutive h-cols -> Hbuf (b64) ----
    #pragma unroll
    for (int ms = 0; ms < 4; ++ms) {
        const int hcol0 = w * 64 + ms * 16 + q * 4;   // 4 consecutive h-cols
        const float* bsrc = (hcol0 < H1) ? (bnb + hcol0) : (bsf + (hcol0 - H1));
        const float4 bb = *((const float4*)bsrc);
        const int kc2 = hcol0 >> 5;
        const int q2  = (hcol0 >> 3) & 3;
        const int j0  = hcol0 & 7;
        #pragma unroll
        for (int ns = 0; ns < 4; ++ns) {
            const f32x4 a = acc1[ms][ns];
            const float v0 = fmaxf(a.x + bb.x, 0.f);
            const float v1 = fmaxf(a.y + bb.y, 0.f);
            const float v2 = fmaxf(a.z + bb.z, 0.f);
            const float v3 = fmaxf(a.w + bb.w, 0.f);
            const int idx = ((ns * 8 + kc2) * 64 + (q2 * 16 + m)) * 8 + j0;
            uint2 p; p.x = bfpack(v0, v1); p.y = bfpack(v2, v3);
            *((uint2*)&Hbuf[idx]) = p;
        }
    }

    // ---- pre-gather W2 B-fragments (wave w -> a1 cols (w<2) or a2 cols) ----
    const int kbase = (w < 2) ? 0 : H1;     // row offset into Wat1 (256 x 64)
    FragU w2f[2][4];                        // [out-col subtile][k chunk], 32 VGPRs
    #pragma unroll
    for (int ns2 = 0; ns2 < 2; ++ns2) {
        const int col2 = (w & 1) * 32 + ns2 * 16 + m;   // 0..63
        #pragma unroll
        for (int kc = 0; kc < 4; ++kc) {
            const int k0 = kbase + kc * 32 + q * 8;
            float e[8];
            #pragma unroll
            for (int j = 0; j < 8; ++j) e[j] = Wat1[(size_t)(k0 + j) * H2 + col2];
            w2f[ns2][kc].u = make_uint4(bfpack(e[0], e[1]), bfpack(e[2], e[3]),
                                        bfpack(e[4], e[5]), bfpack(e[6], e[7]));
        }
    }

    f32x4 acc2[4][2];                       // [node subtile][out-col subtile]
    #pragma unroll
    for (int i = 0; i < 4; ++i) { acc2[i][0] = (f32x4){0.f,0.f,0.f,0.f};
                                  acc2[i][1] = (f32x4){0.f,0.f,0.f,0.f}; }

    __syncthreads();

    // ---- stage 2: D = H * W2half (normal orientation) ----
    #pragma unroll
    for (int kc = 0; kc < 4; ++kc) {
        const int kc2 = kc + ((w < 2) ? 0 : 4);   // h1 cols for a1, h2 for a2
        #pragma unroll
        for (int ms = 0; ms < 4; ++ms) {
            FragU hf; hf.u = *((const uint4*)&Hbuf[((ms * 8 + kc2) * 64 + lane) * 8]);
            #pragma unroll
            for (int ns2 = 0; ns2 < 2; ++ns2)
                acc2[ms][ns2] = __builtin_amdgcn_mfma_f32_16x16x32_bf16(
                    hf.v, w2f[ns2][kc].v, acc2[ms][ns2], 0, 0, 0);
        }
    }

    // ---- epilogue 2: (+bat1 for a1), cvt bf16, store ----
    u16* aout = (w < 2) ? a1 : a2;
    #pragma unroll
    for (int ns2 = 0; ns2 < 2; ++ns2) {
        const int col2 = (w & 1) * 32 + ns2 * 16 + m;
        const float b2 = (w < 2) ? bat1[col2] : 0.f;
        #pragma unroll
        for (int ms = 0; ms < 4; ++ms) {
            const f32x4 a = acc2[ms][ns2];
            const int gn0 = n0 + ms * 16 + q * 4;
            if (gn0 + 0 < N_NODES) aout[(size_t)(gn0 + 0) * H2 + col2] = f2bf(a.x + b2);
            if (gn0 + 1 < N_NODES) aout[(size_t)(gn0 + 1) * H2 + col2] = f2bf(a.y + b2);
            if (gn0 + 2 < N_NODES) aout[(size_t)(gn0 + 2) * H2 + col2] = f2bf(a.z + b2);
            if (gn0 + 3 < N_NODES) aout[(size_t)(gn0 + 3) * H2 + col2] = f2bf(a.w + b2);
        }
    }
}

// 8 lanes per edge, 2 edges per thread (MLP: 4 independent 16B gathers in flight).
__global__ __launch_bounds__(256) void edge_kernel(
    const int* __restrict__ edges,
    const u16* __restrict__ a1, const u16* __restrict__ a2,
    const float* __restrict__ Wat2, const float* __restrict__ bat2,
    float* __restrict__ out)
{
    const int t  = threadIdx.x;
    const int l  = t & 7;
    const int g  = t >> 3;
    const int e0 = blockIdx.x * 64 + g;       // 9375 * 64 == 600000 exactly
    const int e1 = e0 + 32;

    const float4 w0 = ((const float4*)Wat2)[l * 2 + 0];
    const float4 w1 = ((const float4*)Wat2)[l * 2 + 1];
    const float  bias = bat2[0];

    const int2 pa = ((const int2*)edges)[e0];
    const int2 pb = ((const int2*)edges)[e1];
    const uint4 qa1 = ((const uint4*)(a1 + (size_t)pa.x * H2))[l];
    const uint4 qa2 = ((const uint4*)(a2 + (size_t)pa.y * H2))[l];
    const uint4 qb1 = ((const uint4*)(a1 + (size_t)pb.x * H2))[l];
    const uint4 qb2 = ((const uint4*)(a2 + (size_t)pb.y * H2))[l];

    float sa = 0.f, sb = 0.f;
    sa += fmaxf(bflo(qa1.x) + bflo(qa2.x), 0.f) * w0.x;
    sa += fmaxf(bfhi(qa1.x) + bfhi(qa2.x), 0.f) * w0.y;
    sa += fmaxf(bflo(qa1.y) + bflo(qa2.y), 0.f) * w0.z;
    sa += fmaxf(bfhi(qa1.y) + bfhi(qa2.y), 0.f) * w0.w;
    sa += fmaxf(bflo(qa1.z) + bflo(qa2.z), 0.f) * w1.x;
    sa += fmaxf(bfhi(qa1.z) + bfhi(qa2.z), 0.f) * w1.y;
    sa += fmaxf(bflo(qa1.w) + bflo(qa2.w), 0.f) * w1.z;
    sa += fmaxf(bfhi(qa1.w) + bfhi(qa2.w), 0.f) * w1.w;

    sb += fmaxf(bflo(qb1.x) + bflo(qb2.x), 0.f) * w0.x;
    sb += fmaxf(bfhi(qb1.x) + bfhi(qb2.x), 0.f) * w0.y;
    sb += fmaxf(bflo(qb1.y) + bflo(qb2.y), 0.f) * w0.z;
    sb += fmaxf(bfhi(qb1.y) + bfhi(qb2.y), 0.f) * w0.w;
    sb += fmaxf(bflo(qb1.z) + bflo(qb2.z), 0.f) * w1.x;
    sb += fmaxf(bfhi(qb1.z) + bfhi(qb2.z), 0.f) * w1.y;
    sb += fmaxf(bflo(qb1.w) + bflo(qb2.w), 0.f) * w1.z;
    sb += fmaxf(bfhi(qb1.w) + bfhi(qb2.w), 0.f) * w1.w;

    sa += __shfl_down(sa, 4, 8); sb += __shfl_down(sb, 4, 8);
    sa += __shfl_down(sa, 2, 8); sb += __shfl_down(sb, 2, 8);
    sa += __shfl_down(sa, 1, 8); sb += __shfl_down(sb, 1, 8);

    if (l == 0) { out[e0] = sa + bias; out[e1] = sb + bias; }
}

extern "C" void kernel_launch(void* const* d_in, const int* in_sizes, int n_in,
                              void* d_out, int out_size, void* d_ws, size_t ws_size,
                              hipStream_t stream) {
    const float* feat  = (const float*)d_in[0];
    const int*   edges = (const int*)d_in[1];
    const float* Wnb   = (const float*)d_in[2];
    const float* bnb   = (const float*)d_in[3];
    const float* Wsf   = (const float*)d_in[4];
    const float* bsf   = (const float*)d_in[5];
    const float* Wat1  = (const float*)d_in[6];
    const float* bat1  = (const float*)d_in[7];
    const float* Wat2  = (const float*)d_in[8];
    const float* bat2  = (const float*)d_in[9];
    float* out = (float*)d_out;

    u16* a1 = (u16*)d_ws;                       // 50000*64 bf16 = 6.4 MB
    u16* a2 = a1 + (size_t)N_NODES * H2;        // +6.4 MB

    const int node_blocks = (N_NODES + 63) / 64;   // 782
    node_kernel<<<node_blocks, 256, 0, stream>>>(feat, Wnb, bnb, Wsf, bsf,
                                                 Wat1, bat1, a1, a2);

    const int edge_blocks = N_EDGES / 64;          // 9375
    edge_kernel<<<edge_blocks, 256, 0, stream>>>(edges, a1, a2, Wat2, bat2, out);
}

// Round 4
// 125.827 us; speedup vs baseline: 4.8947x; 1.0239x over previous
//
#include <hip/hip_runtime.h>

// edgeNet, round 4.
//   a1[n] = relu(feat[n]@W_nb  + b_nb ) @ W_att1[:128] + b_att1
//   a2[n] = relu(feat[n]@W_self+ b_self) @ W_att1[128:]
//   out[e] = relu(a1[e0] + a2[e1]) . W_att2 + b_att2
//
// r4 changes vs r3:
//  - prep_kernel pre-packs weights into bf16 fragment-major buffers ONCE per
//    call; node_kernel loads fragments as coalesced uint4 (was: 192 strided
//    scalar loads + ~600 pack-VALU per thread, redundantly per block).
//  - stage 2 computed operand-SWAPPED (D' = W2^T * H^T). The existing w2f/hf
//    fragments are valid A/B operands for the swapped product unchanged; the
//    epilogue then holds 4 consecutive out-cols per lane -> ushort4 stores
//    (was 32x scalar 2B stores).
//  - edge kernel: 4 edges/thread for gather MLP.

#define N_NODES 50000
#define D_FEAT  128
#define H1      128
#define H2      64
#define N_EDGES 600000

typedef unsigned short u16;
typedef __attribute__((ext_vector_type(8))) short bf16x8;
typedef __attribute__((ext_vector_type(4))) float f32x4;

union FragU { uint4 u; bf16x8 v; };

static __device__ __forceinline__ unsigned bfpack(float a, float b) {
    union { float f; unsigned u; } x, y; x.f = a; y.f = b;
    unsigned lo = (x.u + 0x7fffu + ((x.u >> 16) & 1u)) >> 16;
    unsigned hi = (y.u + 0x7fffu + ((y.u >> 16) & 1u)) & 0xffff0000u;
    return lo | hi;
}
static __device__ __forceinline__ u16 f2bf(float f) {
    union { float f; unsigned u; } v; v.f = f;
    return (u16)((v.u + 0x7fffu + ((v.u >> 16) & 1u)) >> 16);
}
static __device__ __forceinline__ float bflo(unsigned u) {
    union { unsigned u; float f; } v; v.u = u << 16; return v.f;
}
static __device__ __forceinline__ float bfhi(unsigned u) {
    union { unsigned u; float f; } v; v.u = u & 0xffff0000u; return v.f;
}

// ---------------------------------------------------------------------------
// prep: pack W1 = [Wnb | Wsf] (128x128 each) and Wat1 (256x64) into bf16
// fragment-major layouts.
//   W1F slot ((cs*4 + kc)*64 + q*16 + m)*8 + j  = W1[k = kc*32+q*8+j][col = cs*16+m]
//   W2F slot ((cs2*8 + kc)*64 + q*16 + m)*8 + j = Wat1[k = kc*32+q*8+j][col2 = cs2*16+m]
// Blocks 0..15: W1F (cs = blockIdx). Block 16: all of W2F.
// ---------------------------------------------------------------------------
__global__ __launch_bounds__(256) void prep_kernel(
    const float* __restrict__ Wnb, const float* __restrict__ Wsf,
    const float* __restrict__ Wat1,
    u16* __restrict__ W1F, u16* __restrict__ W2F)
{
    const int t = threadIdx.x;
    const int b = blockIdx.x;
    if (b < 16) {
        const int cs = b;
        const int kc = t >> 6, q = (t >> 4) & 3, m = t & 15;
        const int col = cs * 16 + m;
        const float* src = (col < H1) ? (Wnb + col) : (Wsf + (col - H1));
        const int k0 = kc * 32 + q * 8;
        float e[8];
        #pragma unroll
        for (int j = 0; j < 8; ++j) e[j] = src[(size_t)(k0 + j) * H1];
        uint4 pk = make_uint4(bfpack(e[0], e[1]), bfpack(e[2], e[3]),
                              bfpack(e[4], e[5]), bfpack(e[6], e[7]));
        *((uint4*)&W1F[((cs * 4 + kc) * 64 + q * 16 + m) * 8]) = pk;
    } else {
        for (int i = t; i < 4 * 8 * 64; i += 256) {
            const int lane = i & 63, pair = i >> 6;          // pair = cs2*8 + kc
            const int kc = pair & 7, cs2 = pair >> 3;
            const int q = lane >> 4, m = lane & 15;
            const int col2 = cs2 * 16 + m;
            const int k0 = kc * 32 + q * 8;
            float e[8];
            #pragma unroll
            for (int j = 0; j < 8; ++j) e[j] = Wat1[(size_t)(k0 + j) * H2 + col2];
            uint4 pk = make_uint4(bfpack(e[0], e[1]), bfpack(e[2], e[3]),
                                  bfpack(e[4], e[5]), bfpack(e[6], e[7]));
            *((uint4*)&W2F[(pair * 64 + lane) * 8]) = pk;
        }
    }
}

// ---------------------------------------------------------------------------
// node kernel: 64 nodes/block, 4 waves, bf16 MFMA 16x16x32.
// Stage 1 swapped: D' = W1^T * F^T  (C/D rows = h-cols -> packed Hbuf writes).
// Stage 2 swapped: D' = W2^T * H^T  (C/D rows = out-cols -> ushort4 stores).
// ---------------------------------------------------------------------------
__global__ __launch_bounds__(256) void node_kernel(
    const float* __restrict__ feat,
    const u16* __restrict__ W1F,  const u16* __restrict__ W2F,
    const float* __restrict__ bnb,  const float* __restrict__ bsf,
    const float* __restrict__ bat1,
    u16* __restrict__ a1, u16* __restrict__ a2)
{
    __shared__ u16 Abuf[4 * 4 * 64 * 8];   // features, frag-major (16 KB)
    __shared__ u16 Hbuf[4 * 8 * 64 * 8];   // hidden,   frag-major (32 KB)

    const int t    = threadIdx.x;
    const int w    = t >> 6;
    const int lane = t & 63;
    const int m    = lane & 15;
    const int q    = lane >> 4;
    const int n0   = blockIdx.x * 64;

    // ---- weight fragments: coalesced uint4 loads from frag-major buffers ----
    FragU w1f[4][4];
    #pragma unroll
    for (int ms = 0; ms < 4; ++ms)
        #pragma unroll
        for (int kc = 0; kc < 4; ++kc)
            w1f[ms][kc].u = *((const uint4*)&W1F[(((w * 4 + ms) * 4 + kc) * 64 + lane) * 8]);

    // ---- stage features -> bf16, A-frag-major ----
    #pragma unroll
    for (int s = 0; s < 8; ++s) {
        const int i   = s * 256 + t;
        const int row = i >> 5;
        const int c4  = i & 31;
        const int gn  = n0 + row;
        float4 v = make_float4(0.f, 0.f, 0.f, 0.f);
        if (gn < N_NODES)
            v = *((const float4*)(feat + (size_t)gn * D_FEAT + c4 * 4));
        const int k0  = c4 * 4;
        const int kc  = k0 >> 5;
        const int qq  = (k0 >> 3) & 3;
        const int j0  = k0 & 7;
        const int idx = (((row >> 4) * 4 + kc) * 64 + (qq * 16 + (row & 15))) * 8 + j0;
        uint2 p; p.x = bfpack(v.x, v.y); p.y = bfpack(v.z, v.w);
        *((uint2*)&Abuf[idx]) = p;
    }

    f32x4 acc1[4][4];
    #pragma unroll
    for (int i = 0; i < 4; ++i)
        #pragma unroll
        for (int j = 0; j < 4; ++j)
            acc1[i][j] = (f32x4){0.f, 0.f, 0.f, 0.f};

    __syncthreads();

    // ---- stage 1 (swapped): h-col x node tiles ----
    #pragma unroll
    for (int kc = 0; kc < 4; ++kc) {
        #pragma unroll
        for (int ns = 0; ns < 4; ++ns) {
            FragU ff; ff.u = *((const uint4*)&Abuf[((ns * 4 + kc) * 64 + lane) * 8]);
            #pragma unroll
            for (int ms = 0; ms < 4; ++ms)
                acc1[ms][ns] = __builtin_amdgcn_mfma_f32_16x16x32_bf16(
                    w1f[ms][kc].v, ff.v, acc1[ms][ns], 0, 0, 0);
        }
    }

    // ---- epilogue 1: bias + relu, pack 4 consecutive h-cols -> Hbuf ----
    #pragma unroll
    for (int ms = 0; ms < 4; ++ms) {
        const int hcol0 = w * 64 + ms * 16 + q * 4;
        const float* bsrc = (hcol0 < H1) ? (bnb + hcol0) : (bsf + (hcol0 - H1));
        const float4 bb = *((const float4*)bsrc);
        const int kc2 = hcol0 >> 5;
        const int q2  = (hcol0 >> 3) & 3;
        const int j0  = hcol0 & 7;
        #pragma unroll
        for (int ns = 0; ns < 4; ++ns) {
            const f32x4 a = acc1[ms][ns];
            const float v0 = fmaxf(a.x + bb.x, 0.f);
            const float v1 = fmaxf(a.y + bb.y, 0.f);
            const float v2 = fmaxf(a.z + bb.z, 0.f);
            const float v3 = fmaxf(a.w + bb.w, 0.f);
            const int idx = ((ns * 8 + kc2) * 64 + (q2 * 16 + m)) * 8 + j0;
            uint2 p; p.x = bfpack(v0, v1); p.y = bfpack(v2, v3);
            *((uint2*)&Hbuf[idx]) = p;
        }
    }

    // ---- W2 fragments (coalesced) ----
    FragU w2f[2][4];
    #pragma unroll
    for (int ns2 = 0; ns2 < 2; ++ns2) {
        const int cs2 = (w & 1) * 2 + ns2;
        #pragma unroll
        for (int kcl = 0; kcl < 4; ++kcl) {
            const int kc = kcl + ((w < 2) ? 0 : 4);
            w2f[ns2][kcl].u = *((const uint4*)&W2F[((cs2 * 8 + kc) * 64 + lane) * 8]);
        }
    }

    f32x4 acc2[4][2];
    #pragma unroll
    for (int i = 0; i < 4; ++i) { acc2[i][0] = (f32x4){0.f,0.f,0.f,0.f};
                                  acc2[i][1] = (f32x4){0.f,0.f,0.f,0.f}; }

    __syncthreads();

    // ---- stage 2 (swapped): D' = W2^T * H^T ----
    #pragma unroll
    for (int kcl = 0; kcl < 4; ++kcl) {
        const int kc2 = kcl + ((w < 2) ? 0 : 4);   // h1 cols for a1, h2 for a2
        #pragma unroll
        for (int ms = 0; ms < 4; ++ms) {
            FragU hf; hf.u = *((const uint4*)&Hbuf[((ms * 8 + kc2) * 64 + lane) * 8]);
            #pragma unroll
            for (int ns2 = 0; ns2 < 2; ++ns2)
                acc2[ms][ns2] = __builtin_amdgcn_mfma_f32_16x16x32_bf16(
                    w2f[ns2][kcl].v, hf.v, acc2[ms][ns2], 0, 0, 0);
        }
    }

    // ---- epilogue 2: 4 consecutive out-cols per lane -> ushort4 stores ----
    u16* aout = (w < 2) ? a1 : a2;
    const int colbase = (w & 1) * 32;
    #pragma unroll
    for (int ns2 = 0; ns2 < 2; ++ns2) {
        const int c0 = colbase + ns2 * 16 + q * 4;
        float4 b2 = make_float4(0.f, 0.f, 0.f, 0.f);
        if (w < 2) b2 = *((const float4*)(bat1 + c0));
        #pragma unroll
        for (int ms = 0; ms < 4; ++ms) {
            const int node = n0 + ms * 16 + m;
            if (node < N_NODES) {
                const f32x4 a = acc2[ms][ns2];
                ushort4 pk;
                pk.x = f2bf(a.x + b2.x); pk.y = f2bf(a.y + b2.y);
                pk.z = f2bf(a.z + b2.z); pk.w = f2bf(a.w + b2.w);
                *((ushort4*)(aout + (size_t)node * H2 + c0)) = pk;
            }
        }
    }
}

// ---------------------------------------------------------------------------
// edge kernel: 8 lanes/edge, 4 edges/thread (8 gathers of 16B in flight).
// ---------------------------------------------------------------------------
static __device__ __forceinline__ float edot(uint4 q1, uint4 q2,
                                             float4 w0, float4 w1) {
    float s = 0.f;
    s += fmaxf(bflo(q1.x) + bflo(q2.x), 0.f) * w0.x;
    s += fmaxf(bfhi(q1.x) + bfhi(q2.x), 0.f) * w0.y;
    s += fmaxf(bflo(q1.y) + bflo(q2.y), 0.f) * w0.z;
    s += fmaxf(bfhi(q1.y) + bfhi(q2.y), 0.f) * w0.w;
    s += fmaxf(bflo(q1.z) + bflo(q2.z), 0.f) * w1.x;
    s += fmaxf(bfhi(q1.z) + bfhi(q2.z), 0.f) * w1.y;
    s += fmaxf(bflo(q1.w) + bflo(q2.w), 0.f) * w1.z;
    s += fmaxf(bfhi(q1.w) + bfhi(q2.w), 0.f) * w1.w;
    return s;
}

__global__ __launch_bounds__(256) void edge_kernel(
    const int* __restrict__ edges,
    const u16* __restrict__ a1, const u16* __restrict__ a2,
    const float* __restrict__ Wat2, const float* __restrict__ bat2,
    float* __restrict__ out)
{
    const int t = threadIdx.x;
    const int l = t & 7;
    const int g = t >> 3;                       // 0..31
    const int base = blockIdx.x * 128 + g;

    const float4 w0 = ((const float4*)Wat2)[l * 2 + 0];
    const float4 w1 = ((const float4*)Wat2)[l * 2 + 1];
    const float  bias = bat2[0];

    int  e[4]; bool v[4]; int2 ep[4];
    #pragma unroll
    for (int i = 0; i < 4; ++i) {
        e[i] = base + i * 32;
        v[i] = e[i] < N_EDGES;
        ep[i] = v[i] ? ((const int2*)edges)[e[i]] : make_int2(0, 0);
    }

    uint4 q1[4], q2[4];
    #pragma unroll
    for (int i = 0; i < 4; ++i) {
        q1[i] = ((const uint4*)(a1 + (size_t)ep[i].x * H2))[l];
        q2[i] = ((const uint4*)(a2 + (size_t)ep[i].y * H2))[l];
    }

    float s[4];
    #pragma unroll
    for (int i = 0; i < 4; ++i) {
        s[i] = edot(q1[i], q2[i], w0, w1);
        s[i] += __shfl_down(s[i], 4, 8);
        s[i] += __shfl_down(s[i], 2, 8);
        s[i] += __shfl_down(s[i], 1, 8);
    }

    if (l == 0) {
        #pragma unroll
        for (int i = 0; i < 4; ++i)
            if (v[i]) out[e[i]] = s[i] + bias;
    }
}

extern "C" void kernel_launch(void* const* d_in, const int* in_sizes, int n_in,
                              void* d_out, int out_size, void* d_ws, size_t ws_size,
                              hipStream_t stream) {
    const float* feat  = (const float*)d_in[0];
    const int*   edges = (const int*)d_in[1];
    const float* Wnb   = (const float*)d_in[2];
    const float* bnb   = (const float*)d_in[3];
    const float* Wsf   = (const float*)d_in[4];
    const float* bsf   = (const float*)d_in[5];
    const float* Wat1  = (const float*)d_in[6];
    const float* bat1  = (const float*)d_in[7];
    const float* Wat2  = (const float*)d_in[8];
    const float* bat2  = (const float*)d_in[9];
    float* out = (float*)d_out;

    u16* a1  = (u16*)d_ws;                         // 6.4 MB
    u16* a2  = a1 + (size_t)N_NODES * H2;          // 6.4 MB
    u16* W1F = a2 + (size_t)N_NODES * H2;          // 64 KB (16*4*64*8 u16)
    u16* W2F = W1F + 16 * 4 * 64 * 8;              // 32 KB (4*8*64*8 u16)

    prep_kernel<<<17, 256, 0, stream>>>(Wnb, Wsf, Wat1, W1F, W2F);

    const int node_blocks = (N_NODES + 63) / 64;   // 782
    node_kernel<<<node_blocks, 256, 0, stream>>>(feat, W1F, W2F,
                                                 bnb, bsf, bat1, a1, a2);

    const int edge_blocks = (N_EDGES + 127) / 128; // 4688
    edge_kernel<<<edge_blocks, 256, 0, stream>>>(edges, a1, a2, Wat2, bat2, out);
}

// Round 5
// 123.390 us; speedup vs baseline: 4.9914x; 1.0198x over previous
//
#include <hip/hip_runtime.h>

// edgeNet, round 5.
//   a1[n] = relu(feat[n]@W_nb  + b_nb ) @ W_att1[:128] + b_att1
//   a2[n] = relu(feat[n]@W_self+ b_self) @ W_att1[128:]
//   out[e] = relu(a1[e0] + a2[e1]) . W_att2 + b_att2
//
// r5 changes vs r4:
//  - whole pipeline bf16 -> f16 (same MFMA rate, 10-bit mantissa -> better
//    absmax margin; values are O(1), no range risk).
//  - feature staging threads realigned to fragment slots: each thread packs
//    one full uint4 frag slot and writes it lane-contiguously (was: uint2
//    writes at 16-way bank conflict; 4 iters instead of 8).
//  - edge kernel: v_pk_add_f16/v_pk_max_f16 + cvt instead of per-element
//    shift/mask bf16 math (24 VALU vs 40 per lane-edge).

#define N_NODES 50000
#define D_FEAT  128
#define H1      128
#define H2      64
#define N_EDGES 600000

typedef unsigned short u16;
typedef _Float16 f16;
typedef __attribute__((ext_vector_type(8))) _Float16 f16x8;
typedef __attribute__((ext_vector_type(2))) _Float16 f16x2;
typedef __attribute__((ext_vector_type(2))) float f32x2;
typedef __attribute__((ext_vector_type(4))) float f32x4;

union FragH { uint4 u; f16x8 v; };
union H2U   { unsigned u; f16x2 h; };

static __device__ __forceinline__ u16 f2h(float f) {
    union { f16 h; u16 u; } v; v.h = (f16)f; return v.u;   // v_cvt_f16_f32, RTN
}
static __device__ __forceinline__ unsigned hpack(float a, float b) {
    return (unsigned)f2h(a) | ((unsigned)f2h(b) << 16);
}

// ---------------------------------------------------------------------------
// prep: pack W1 = [Wnb | Wsf] (128x128 each) and Wat1 (256x64) into f16
// fragment-major layouts.
//   W1F slot ((cs*4 + kc)*64 + q*16 + m)*8 + j  = W1[k = kc*32+q*8+j][col = cs*16+m]
//   W2F slot ((cs2*8 + kc)*64 + q*16 + m)*8 + j = Wat1[k = kc*32+q*8+j][col2 = cs2*16+m]
// ---------------------------------------------------------------------------
__global__ __launch_bounds__(256) void prep_kernel(
    const float* __restrict__ Wnb, const float* __restrict__ Wsf,
    const float* __restrict__ Wat1,
    u16* __restrict__ W1F, u16* __restrict__ W2F)
{
    const int t = threadIdx.x;
    const int b = blockIdx.x;
    if (b < 16) {
        const int cs = b;
        const int kc = t >> 6, q = (t >> 4) & 3, m = t & 15;
        const int col = cs * 16 + m;
        const float* src = (col < H1) ? (Wnb + col) : (Wsf + (col - H1));
        const int k0 = kc * 32 + q * 8;
        float e[8];
        #pragma unroll
        for (int j = 0; j < 8; ++j) e[j] = src[(size_t)(k0 + j) * H1];
        uint4 pk = make_uint4(hpack(e[0], e[1]), hpack(e[2], e[3]),
                              hpack(e[4], e[5]), hpack(e[6], e[7]));
        *((uint4*)&W1F[((cs * 4 + kc) * 64 + q * 16 + m) * 8]) = pk;
    } else {
        for (int i = t; i < 4 * 8 * 64; i += 256) {
            const int lane = i & 63, pair = i >> 6;          // pair = cs2*8 + kc
            const int q = lane >> 4, m = lane & 15;
            const int cs2 = pair >> 3, kc = pair & 7;
            const int col2 = cs2 * 16 + m;
            const int k0 = kc * 32 + q * 8;
            float e[8];
            #pragma unroll
            for (int j = 0; j < 8; ++j) e[j] = Wat1[(size_t)(k0 + j) * H2 + col2];
            uint4 pk = make_uint4(hpack(e[0], e[1]), hpack(e[2], e[3]),
                                  hpack(e[4], e[5]), hpack(e[6], e[7]));
            *((uint4*)&W2F[(pair * 64 + lane) * 8]) = pk;
        }
    }
}

// ---------------------------------------------------------------------------
// node kernel: 64 nodes/block, 4 waves, f16 MFMA 16x16x32.
// Stage 1 swapped: D' = W1^T * F^T  (C/D rows = h-cols -> packed Hbuf writes).
// Stage 2 swapped: D' = W2^T * H^T  (C/D rows = out-cols -> ushort4 stores).
// ---------------------------------------------------------------------------
__global__ __launch_bounds__(256) void node_kernel(
    const float* __restrict__ feat,
    const u16* __restrict__ W1F,  const u16* __restrict__ W2F,
    const float* __restrict__ bnb,  const float* __restrict__ bsf,
    const float* __restrict__ bat1,
    u16* __restrict__ a1, u16* __restrict__ a2)
{
    __shared__ u16 Abuf[4 * 4 * 64 * 8];   // features, frag-major (16 KB)
    __shared__ u16 Hbuf[4 * 8 * 64 * 8];   // hidden,   frag-major (32 KB)

    const int t    = threadIdx.x;
    const int w    = t >> 6;
    const int lane = t & 63;
    const int m    = lane & 15;
    const int q    = lane >> 4;
    const int n0   = blockIdx.x * 64;

    // ---- stage features -> f16, one full frag slot per thread per iter ----
    // slot = ((it*4 + kc)*64 + q*16 + m) with kc = t>>6, q = (t>>4)&3, m = t&15.
    // Consecutive t -> consecutive slots -> lane-contiguous uint4 writes
    // (conflict-free). Thread reads feat[n0+it*16+m][kc*32+q*8 .. +8] (32 B).
    {
        const int kcs = t >> 6;
        const int k0  = kcs * 32 + q * 8;
        #pragma unroll
        for (int it = 0; it < 4; ++it) {
            const int gn = n0 + it * 16 + m;
            float4 va = make_float4(0.f,0.f,0.f,0.f), vb = va;
            if (gn < N_NODES) {
                const float* src = feat + (size_t)gn * D_FEAT + k0;
                va = *((const float4*)src);
                vb = *((const float4*)(src + 4));
            }
            uint4 pk = make_uint4(hpack(va.x, va.y), hpack(va.z, va.w),
                                  hpack(vb.x, vb.y), hpack(vb.z, vb.w));
            *((uint4*)&Abuf[(((it * 4 + kcs) * 64) + (t & 63)) * 8]) = pk;
        }
    }

    // ---- weight fragments: coalesced uint4 loads from frag-major buffers ----
    FragH w1f[4][4];
    #pragma unroll
    for (int ms = 0; ms < 4; ++ms)
        #pragma unroll
        for (int kc = 0; kc < 4; ++kc)
            w1f[ms][kc].u = *((const uint4*)&W1F[(((w * 4 + ms) * 4 + kc) * 64 + lane) * 8]);

    f32x4 acc1[4][4];
    #pragma unroll
    for (int i = 0; i < 4; ++i)
        #pragma unroll
        for (int j = 0; j < 4; ++j)
            acc1[i][j] = (f32x4){0.f, 0.f, 0.f, 0.f};

    __syncthreads();

    // ---- stage 1 (swapped): h-col x node tiles ----
    #pragma unroll
    for (int kc = 0; kc < 4; ++kc) {
        #pragma unroll
        for (int ns = 0; ns < 4; ++ns) {
            FragH ff; ff.u = *((const uint4*)&Abuf[((ns * 4 + kc) * 64 + lane) * 8]);
            #pragma unroll
            for (int ms = 0; ms < 4; ++ms)
                acc1[ms][ns] = __builtin_amdgcn_mfma_f32_16x16x32_f16(
                    w1f[ms][kc].v, ff.v, acc1[ms][ns], 0, 0, 0);
        }
    }

    // ---- epilogue 1: bias + relu, pack 4 consecutive h-cols -> Hbuf ----
    #pragma unroll
    for (int ms = 0; ms < 4; ++ms) {
        const int hcol0 = w * 64 + ms * 16 + q * 4;
        const float* bsrc = (hcol0 < H1) ? (bnb + hcol0) : (bsf + (hcol0 - H1));
        const float4 bb = *((const float4*)bsrc);
        const int kc2 = hcol0 >> 5;
        const int q2  = (hcol0 >> 3) & 3;
        const int j0  = hcol0 & 7;
        #pragma unroll
        for (int ns = 0; ns < 4; ++ns) {
            const f32x4 a = acc1[ms][ns];
            const float v0 = fmaxf(a.x + bb.x, 0.f);
            const float v1 = fmaxf(a.y + bb.y, 0.f);
            const float v2 = fmaxf(a.z + bb.z, 0.f);
            const float v3 = fmaxf(a.w + bb.w, 0.f);
            const int idx = ((ns * 8 + kc2) * 64 + (q2 * 16 + m)) * 8 + j0;
            uint2 p; p.x = hpack(v0, v1); p.y = hpack(v2, v3);
            *((uint2*)&Hbuf[idx]) = p;
        }
    }

    // ---- W2 fragments (coalesced) ----
    FragH w2f[2][4];
    #pragma unroll
    for (int ns2 = 0; ns2 < 2; ++ns2) {
        const int cs2 = (w & 1) * 2 + ns2;
        #pragma unroll
        for (int kcl = 0; kcl < 4; ++kcl) {
            const int kc = kcl + ((w < 2) ? 0 : 4);
            w2f[ns2][kcl].u = *((const uint4*)&W2F[((cs2 * 8 + kc) * 64 + lane) * 8]);
        }
    }

    f32x4 acc2[4][2];
    #pragma unroll
    for (int i = 0; i < 4; ++i) { acc2[i][0] = (f32x4){0.f,0.f,0.f,0.f};
                                  acc2[i][1] = (f32x4){0.f,0.f,0.f,0.f}; }

    __syncthreads();

    // ---- stage 2 (swapped): D' = W2^T * H^T ----
    #pragma unroll
    for (int kcl = 0; kcl < 4; ++kcl) {
        const int kc2 = kcl + ((w < 2) ? 0 : 4);   // h1 cols for a1, h2 for a2
        #pragma unroll
        for (int ms = 0; ms < 4; ++ms) {
            FragH hf; hf.u = *((const uint4*)&Hbuf[((ms * 8 + kc2) * 64 + lane) * 8]);
            #pragma unroll
            for (int ns2 = 0; ns2 < 2; ++ns2)
                acc2[ms][ns2] = __builtin_amdgcn_mfma_f32_16x16x32_f16(
                    w2f[ns2][kcl].v, hf.v, acc2[ms][ns2], 0, 0, 0);
        }
    }

    // ---- epilogue 2: 4 consecutive out-cols per lane -> ushort4 stores ----
    u16* aout = (w < 2) ? a1 : a2;
    const int colbase = (w & 1) * 32;
    #pragma unroll
    for (int ns2 = 0; ns2 < 2; ++ns2) {
        const int c0 = colbase + ns2 * 16 + q * 4;
        float4 b2 = make_float4(0.f, 0.f, 0.f, 0.f);
        if (w < 2) b2 = *((const float4*)(bat1 + c0));
        #pragma unroll
        for (int ms = 0; ms < 4; ++ms) {
            const int node = n0 + ms * 16 + m;
            if (node < N_NODES) {
                const f32x4 a = acc2[ms][ns2];
                ushort4 pk;
                pk.x = f2h(a.x + b2.x); pk.y = f2h(a.y + b2.y);
                pk.z = f2h(a.z + b2.z); pk.w = f2h(a.w + b2.w);
                *((ushort4*)(aout + (size_t)node * H2 + c0)) = pk;
            }
        }
    }
}

// ---------------------------------------------------------------------------
// edge kernel: 8 lanes/edge, 4 edges/thread. f16 packed math:
// v_pk_add_f16 + v_pk_max_f16 + cvt + fma (24 VALU vs 40 for bf16 shifts).
// ---------------------------------------------------------------------------
static __device__ __forceinline__ float edot(uint4 a, uint4 b,
                                             float4 w0, float4 w1) {
    const f16x2 z = (f16x2)(f16)0;
    float s = 0.f;
    {
        H2U x, y; x.u = a.x; y.u = b.x;
        f16x2 r = __builtin_elementwise_max(x.h + y.h, z);
        f32x2 f = __builtin_convertvector(r, f32x2);
        s = fmaf(f.x, w0.x, fmaf(f.y, w0.y, s));
    }
    {
        H2U x, y; x.u = a.y; y.u = b.y;
        f16x2 r = __builtin_elementwise_max(x.h + y.h, z);
        f32x2 f = __builtin_convertvector(r, f32x2);
        s = fmaf(f.x, w0.z, fmaf(f.y, w0.w, s));
    }
    {
        H2U x, y; x.u = a.z; y.u = b.z;
        f16x2 r = __builtin_elementwise_max(x.h + y.h, z);
        f32x2 f = __builtin_convertvector(r, f32x2);
        s = fmaf(f.x, w1.x, fmaf(f.y, w1.y, s));
    }
    {
        H2U x, y; x.u = a.w; y.u = b.w;
        f16x2 r = __builtin_elementwise_max(x.h + y.h, z);
        f32x2 f = __builtin_convertvector(r, f32x2);
        s = fmaf(f.x, w1.z, fmaf(f.y, w1.w, s));
    }
    return s;
}

__global__ __launch_bounds__(256) void edge_kernel(
    const int* __restrict__ edges,
    const u16* __restrict__ a1, const u16* __restrict__ a2,
    const float* __restrict__ Wat2, const float* __restrict__ bat2,
    float* __restrict__ out)
{
    const int t = threadIdx.x;
    const int l = t & 7;
    const int g = t >> 3;                       // 0..31
    const int base = blockIdx.x * 128 + g;

    const float4 w0 = ((const float4*)Wat2)[l * 2 + 0];
    const float4 w1 = ((const float4*)Wat2)[l * 2 + 1];
    const float  bias = bat2[0];

    int  e[4]; bool v[4]; int2 ep[4];
    #pragma unroll
    for (int i = 0; i < 4; ++i) {
        e[i] = base + i * 32;
        v[i] = e[i] < N_EDGES;
        ep[i] = v[i] ? ((const int2*)edges)[e[i]] : make_int2(0, 0);
    }

    uint4 q1[4], q2[4];
    #pragma unroll
    for (int i = 0; i < 4; ++i) {
        q1[i] = ((const uint4*)(a1 + (size_t)ep[i].x * H2))[l];
        q2[i] = ((const uint4*)(a2 + (size_t)ep[i].y * H2))[l];
    }

    float s[4];
    #pragma unroll
    for (int i = 0; i < 4; ++i) {
        s[i] = edot(q1[i], q2[i], w0, w1);
        s[i] += __shfl_down(s[i], 4, 8);
        s[i] += __shfl_down(s[i], 2, 8);
        s[i] += __shfl_down(s[i], 1, 8);
    }

    if (l == 0) {
        #pragma unroll
        for (int i = 0; i < 4; ++i)
            if (v[i]) out[e[i]] = s[i] + bias;
    }
}

extern "C" void kernel_launch(void* const* d_in, const int* in_sizes, int n_in,
                              void* d_out, int out_size, void* d_ws, size_t ws_size,
                              hipStream_t stream) {
    const float* feat  = (const float*)d_in[0];
    const int*   edges = (const int*)d_in[1];
    const float* Wnb   = (const float*)d_in[2];
    const float* bnb   = (const float*)d_in[3];
    const float* Wsf   = (const float*)d_in[4];
    const float* bsf   = (const float*)d_in[5];
    const float* Wat1  = (const float*)d_in[6];
    const float* bat1  = (const float*)d_in[7];
    const float* Wat2  = (const float*)d_in[8];
    const float* bat2  = (const float*)d_in[9];
    float* out = (float*)d_out;

    u16* a1  = (u16*)d_ws;                         // 6.4 MB (f16)
    u16* a2  = a1 + (size_t)N_NODES * H2;          // 6.4 MB
    u16* W1F = a2 + (size_t)N_NODES * H2;          // 64 KB
    u16* W2F = W1F + 16 * 4 * 64 * 8;              // 32 KB

    prep_kernel<<<17, 256, 0, stream>>>(Wnb, Wsf, Wat1, W1F, W2F);

    const int node_blocks = (N_NODES + 63) / 64;   // 782
    node_kernel<<<node_blocks, 256, 0, stream>>>(feat, W1F, W2F,
                                                 bnb, bsf, bat1, a1, a2);

    const int edge_blocks = (N_EDGES + 127) / 128; // 4688
    edge_kernel<<<edge_blocks, 256, 0, stream>>>(edges, a1, a2, Wat2, bat2, out);
}